// Round 10
// baseline (247.399 us; speedup 1.0000x reference)
//
#include <hip/hip_runtime.h>

// ---------------------------------------------------------------------------
// GCN 2-layer forward, weighted-CSR gather formulation:
//   h  = X @ W                      (raw, bf16, graph-independent)
//   out[i] = dinv[i]^2*h[i] + Σ_{e:dst=i} (dinv[src]*dinv[i])*h[src] + b
// Edge weights stored IN the csr entries (int2 = {src, f32 w}); pads have w=0.
// K1 fuses gemm1 ∥ count_slot (independent) to hide the CSR count pass.
// GEMM1: split-bf16 MFMA (3 MFMA). GEMM2: bf16 A, split W (2 MFMA).
// Dropout mask = JAX threefry2x32, key(42), partitionable fold (o0^o1), p=0.5.
//   (verified rounds 3-9)
// ---------------------------------------------------------------------------

typedef __attribute__((ext_vector_type(8))) short bf16x8;          // MFMA A/B
typedef __attribute__((ext_vector_type(4))) float f32x4;           // MFMA C/D
typedef __attribute__((ext_vector_type(8))) unsigned short us8;

__device__ __forceinline__ unsigned tf_rotl(unsigned x, int d) {
    return (x << d) | (x >> (32 - d));
}

__device__ __forceinline__ bool dropout_keep(unsigned flat_idx) {
    const unsigned K0 = 0u, K1 = 42u;
    const unsigned K2 = K0 ^ K1 ^ 0x1BD11BDAu;
    unsigned x0 = 0u, x1 = flat_idx;
    x0 += K0; x1 += K1;
#define TF_R(r) { x0 += x1; x1 = tf_rotl(x1, (r)); x1 ^= x0; }
    TF_R(13) TF_R(15) TF_R(26) TF_R(6)
    x0 += K1; x1 += K2 + 1u;
    TF_R(17) TF_R(29) TF_R(16) TF_R(24)
    x0 += K2; x1 += K0 + 2u;
    TF_R(13) TF_R(15) TF_R(26) TF_R(6)
    x0 += K0; x1 += K1 + 3u;
    TF_R(17) TF_R(29) TF_R(16) TF_R(24)
    x0 += K1; x1 += K2 + 4u;
    TF_R(13) TF_R(15) TF_R(26) TF_R(6)
    x0 += K2; x1 += K0 + 5u;
#undef TF_R
    return (((x0 ^ x1) >> 31) & 1u) == 0u;   // fold bits1^bits2, keep if < 2^31
}

// ---- bf16 helpers ----------------------------------------------------------
__device__ __forceinline__ unsigned short bf16_rn(float x) {
    unsigned u = __float_as_uint(x);
    unsigned r = u + 0x7FFFu + ((u >> 16) & 1u);
    return (unsigned short)(r >> 16);
}
__device__ __forceinline__ void split_bf16(float x, unsigned short& h, unsigned short& l) {
    h = bf16_rn(x);
    float fh = __uint_as_float(((unsigned)h) << 16);
    l = bf16_rn(x - fh);
}
__device__ __forceinline__ void split4(float4 v, ushort4& h, ushort4& l) {
    unsigned short h0, h1, h2, h3, l0, l1, l2, l3;
    split_bf16(v.x, h0, l0); split_bf16(v.y, h1, l1);
    split_bf16(v.z, h2, l2); split_bf16(v.w, h3, l3);
    h = make_ushort4(h0, h1, h2, h3);
    l = make_ushort4(l0, l1, l2, l3);
}

// int32 vs int64 edge-index autodetect (values < 50000 -> i64 hi words are 0).
__device__ __forceinline__ int ei_stride(const int* __restrict__ ei) {
    bool i64 = true;
#pragma unroll
    for (int k = 1; k <= 15; k += 2) i64 = i64 && (ei[k] == 0);
    return i64 ? 2 : 1;
}

// ---------------------------------------------------------------------------
// gemm core: Yb[r, NOUT_] = bf16( X[r,:] @ W ), MFMA 16x16x32, BM=64, BK=32.
// ---------------------------------------------------------------------------
template <int K_, int NOUT_, bool SPLITA>
__device__ __forceinline__ void gemm_core(const void* __restrict__ Xv,
                                          const unsigned short* __restrict__ wT_hi,
                                          const unsigned short* __restrict__ wT_lo,
                                          unsigned short* __restrict__ Yb,
                                          int nrows, int bid) {
    constexpr int BM = 64, BK = 32, NKT = K_ / BK;
    constexpr int CT = NOUT_ / 64;            // col-tiles per wave
    constexpr int LDW = BK + 8;               // 80B row stride (16B multiple)
    constexpr int WPT = NOUT_ / 32;           // ushort4/thread/half for W staging

    __shared__ __attribute__((aligned(16))) unsigned short xs_hi[BM][LDW];
    __shared__ __attribute__((aligned(16))) unsigned short xs_lo[SPLITA ? BM : 1][SPLITA ? LDW : 1];
    __shared__ __attribute__((aligned(16))) unsigned short ws_hi[NOUT_][LDW];
    __shared__ __attribute__((aligned(16))) unsigned short ws_lo[NOUT_][LDW];

    const int t = threadIdx.x;
    const int wave = t >> 6, lane = t & 63;
    const int m16 = lane & 15, kg = lane >> 4;
    const int row0 = bid * BM;
    const int n0 = wave * (16 * CT);

    const float* Xf = (const float*)Xv;
    const unsigned short* Xb = (const unsigned short*)Xv;

    f32x4 acc[4][CT];
#pragma unroll
    for (int r = 0; r < 4; ++r)
#pragma unroll
        for (int c = 0; c < CT; ++c) acc[r][c] = {0.f, 0.f, 0.f, 0.f};

    float4 xpre[2];
    us8 xpre_b;
    ushort4 wpre_h[WPT], wpre_l[WPT];

    if constexpr (SPLITA) {
#pragma unroll
        for (int i = 0; i < 2; ++i) {
            int idx = t + i * 256;
            int r = idx >> 3, c4 = idx & 7;
            int gr = row0 + r;
            xpre[i] = (gr < nrows) ? *(const float4*)&Xf[(size_t)gr * K_ + c4 * 4]
                                   : make_float4(0.f, 0.f, 0.f, 0.f);
        }
    } else {
        int r = t >> 2, c8 = t & 3;
        int gr = row0 + r;
        xpre_b = (gr < nrows) ? *(const us8*)&Xb[(size_t)gr * K_ + c8 * 8] : (us8)0;
    }
#pragma unroll
    for (int i = 0; i < WPT; ++i) {
        int idx = t + i * 256;
        int n = idx >> 3, c4 = idx & 7;
        wpre_h[i] = *(const ushort4*)&wT_hi[(size_t)n * K_ + c4 * 4];
        wpre_l[i] = *(const ushort4*)&wT_lo[(size_t)n * K_ + c4 * 4];
    }

    for (int kb = 0; kb < NKT; ++kb) {
        if constexpr (SPLITA) {
#pragma unroll
            for (int i = 0; i < 2; ++i) {
                int idx = t + i * 256;
                int r = idx >> 3, c4 = idx & 7;
                ushort4 h, l;
                split4(xpre[i], h, l);
                *(ushort4*)&xs_hi[r][c4 * 4] = h;
                *(ushort4*)&xs_lo[r][c4 * 4] = l;
            }
        } else {
            int r = t >> 2, c8 = t & 3;
            *(us8*)&xs_hi[r][c8 * 8] = xpre_b;
        }
#pragma unroll
        for (int i = 0; i < WPT; ++i) {
            int idx = t + i * 256;
            int n = idx >> 3, c4 = idx & 7;
            *(ushort4*)&ws_hi[n][c4 * 4] = wpre_h[i];
            *(ushort4*)&ws_lo[n][c4 * 4] = wpre_l[i];
        }
        __syncthreads();

        if (kb + 1 < NKT) {
            const int koff = (kb + 1) * BK;
            if constexpr (SPLITA) {
#pragma unroll
                for (int i = 0; i < 2; ++i) {
                    int idx = t + i * 256;
                    int r = idx >> 3, c4 = idx & 7;
                    int gr = row0 + r;
                    xpre[i] = (gr < nrows) ? *(const float4*)&Xf[(size_t)gr * K_ + koff + c4 * 4]
                                           : make_float4(0.f, 0.f, 0.f, 0.f);
                }
            } else {
                int r = t >> 2, c8 = t & 3;
                int gr = row0 + r;
                xpre_b = (gr < nrows) ? *(const us8*)&Xb[(size_t)gr * K_ + koff + c8 * 8] : (us8)0;
            }
#pragma unroll
            for (int i = 0; i < WPT; ++i) {
                int idx = t + i * 256;
                int n = idx >> 3, c4 = idx & 7;
                wpre_h[i] = *(const ushort4*)&wT_hi[(size_t)n * K_ + koff + c4 * 4];
                wpre_l[i] = *(const ushort4*)&wT_lo[(size_t)n * K_ + koff + c4 * 4];
            }
        }

        bf16x8 bh[CT], bl[CT];
#pragma unroll
        for (int c = 0; c < CT; ++c) {
            bh[c] = *(const bf16x8*)&ws_hi[n0 + c * 16 + m16][kg * 8];
            bl[c] = *(const bf16x8*)&ws_lo[n0 + c * 16 + m16][kg * 8];
        }
#pragma unroll
        for (int r = 0; r < 4; ++r) {
            bf16x8 ah = *(const bf16x8*)&xs_hi[r * 16 + m16][kg * 8];
            if constexpr (SPLITA) {
                bf16x8 al = *(const bf16x8*)&xs_lo[r * 16 + m16][kg * 8];
#pragma unroll
                for (int c = 0; c < CT; ++c) {
                    acc[r][c] = __builtin_amdgcn_mfma_f32_16x16x32_bf16(ah, bh[c], acc[r][c], 0, 0, 0);
                    acc[r][c] = __builtin_amdgcn_mfma_f32_16x16x32_bf16(ah, bl[c], acc[r][c], 0, 0, 0);
                    acc[r][c] = __builtin_amdgcn_mfma_f32_16x16x32_bf16(al, bh[c], acc[r][c], 0, 0, 0);
                }
            } else {
#pragma unroll
                for (int c = 0; c < CT; ++c) {
                    acc[r][c] = __builtin_amdgcn_mfma_f32_16x16x32_bf16(ah, bh[c], acc[r][c], 0, 0, 0);
                    acc[r][c] = __builtin_amdgcn_mfma_f32_16x16x32_bf16(ah, bl[c], acc[r][c], 0, 0, 0);
                }
            }
        }
        __syncthreads();
    }

#pragma unroll
    for (int r = 0; r < 4; ++r) {
#pragma unroll
        for (int j = 0; j < 4; ++j) {
            int gr = row0 + r * 16 + kg * 4 + j;
            if (gr < nrows) {
#pragma unroll
                for (int c = 0; c < CT; ++c)
                    Yb[(size_t)gr * NOUT_ + n0 + c * 16 + m16] = bf16_rn(acc[r][c][j]);
            }
        }
    }
}

// ---------------------------------------------------------------------------
// K0: weight split (blocks 0..159) ∥ deg zeroing (rest). Must precede mega1
// (gemm reads wT; count reads deg) — separate kernel avoids intra-kernel race.
// ---------------------------------------------------------------------------
__global__ __launch_bounds__(256)
void prep(const float* __restrict__ W1, const float* __restrict__ W2,
          unsigned short* __restrict__ wT1_hi, unsigned short* __restrict__ wT1_lo,
          unsigned short* __restrict__ wT2_hi, unsigned short* __restrict__ wT2_lo,
          unsigned* __restrict__ deg, int N) {
    const int b = blockIdx.x, t = threadIdx.x;
    if (b < 160) {
        int idx = b * 256 + t;
        unsigned short h, l;
        if (idx < 256 * 128) {
            int k = idx / 128, n = idx % 128;
            split_bf16(W1[idx], h, l);
            wT1_hi[(size_t)n * 256 + k] = h;
            wT1_lo[(size_t)n * 256 + k] = l;
        } else if (idx < 256 * 128 + 128 * 64) {
            int j = idx - 256 * 128;
            int k = j / 64, n = j % 64;
            split_bf16(W2[j], h, l);
            wT2_hi[(size_t)n * 128 + k] = h;
            wT2_lo[(size_t)n * 128 + k] = l;
        }
    } else {
        int i = (b - 160) * 256 + t;
        if (i < N) deg[i] = 0;
    }
}

// ---------------------------------------------------------------------------
// K1: gemm1 (blocks 0..nGemm-1) ∥ count_slot (rest). Independent roles.
// ---------------------------------------------------------------------------
__global__ __launch_bounds__(256)
void mega1(const float* __restrict__ x, const unsigned short* __restrict__ wT1_hi,
           const unsigned short* __restrict__ wT1_lo, unsigned short* __restrict__ buffA,
           const int* __restrict__ ei, unsigned* __restrict__ deg,
           unsigned* __restrict__ aux, int N, int E, int nGemm) {
    if ((int)blockIdx.x < nGemm) {
        gemm_core<256, 128, true>(x, wT1_hi, wT1_lo, buffA, N, blockIdx.x);
        return;
    }
    int e = (blockIdx.x - nGemm) * 256 + threadIdx.x;
    if (e >= E) return;
    size_t st = ei_stride(ei);
    aux[e] = atomicAdd(&deg[ei[((size_t)E + e) * st]], 1u);
}

// ---------------------------------------------------------------------------
// scan phase1: per-block padded-deg sums + dinv.  phase3b: inline scan of the
// (<=256) block sums + local scan -> rowptr; writes pad slots (w=0) into csr2.
// ---------------------------------------------------------------------------
__global__ __launch_bounds__(256)
void scan_phase1(const unsigned* __restrict__ deg, unsigned* __restrict__ blockSums,
                 float* __restrict__ dinv, int N) {
    const int i = blockIdx.x * 256 + threadIdx.x;
    const int lane = threadIdx.x & 63, wave = threadIdx.x >> 6;
    unsigned v = 0;
    if (i < N) {
        unsigned d = deg[i];
        v = (d + 7u) & ~7u;
        dinv[i] = rsqrtf((float)(d + 1u));   // +1 = self loop
    }
    unsigned s = v;
#pragma unroll
    for (int o = 32; o > 0; o >>= 1) s += __shfl_down(s, o, 64);
    __shared__ unsigned ws[4];
    if (lane == 0) ws[wave] = s;
    __syncthreads();
    if (threadIdx.x == 0)
        blockSums[blockIdx.x] = ws[0] + ws[1] + ws[2] + ws[3];
}

__global__ __launch_bounds__(256)
void scan_phase3b(const unsigned* __restrict__ deg, const unsigned* __restrict__ blockSums,
                  unsigned* __restrict__ rowptr, int2* __restrict__ csr2, int N, int nb) {
    __shared__ unsigned s[256];
    const int t = threadIdx.x;

    // inline scan of block sums (nb <= 256 for N <= 65536)
    unsigned bsv = (t < nb) ? blockSums[t] : 0u;
    s[t] = bsv;
    __syncthreads();
    for (int off = 1; off < 256; off <<= 1) {
        unsigned u = (t >= off) ? s[t - off] : 0u;
        __syncthreads();
        s[t] += u;
        __syncthreads();
    }
    const unsigned off0 = (blockIdx.x == 0) ? 0u : s[blockIdx.x - 1];
    __syncthreads();

    // local scan of padded degrees
    const int i = blockIdx.x * 256 + t;
    unsigned d = 0, v = 0;
    if (i < N) { d = deg[i]; v = (d + 7u) & ~7u; }
    s[t] = v;
    __syncthreads();
    for (int off = 1; off < 256; off <<= 1) {
        unsigned u = (t >= off) ? s[t - off] : 0u;
        __syncthreads();
        s[t] += u;
        __syncthreads();
    }
    const unsigned incl = s[t];
    if (i < N) {
        const unsigned rp = off0 + incl - v;
        rowptr[i] = rp;
        if (i == N - 1) rowptr[N] = off0 + incl;
        for (unsigned u = d; u < v; ++u) csr2[rp + u] = make_int2(0, 0);  // w=0 pad
    }
}

// atomic-free placement: csr2[slot] = {src, dinv[src]*dinv[dst]}
__global__ void place_edges(const int* __restrict__ ei, const unsigned* __restrict__ rowptr,
                            const unsigned* __restrict__ aux, const float* __restrict__ dinv,
                            int2* __restrict__ csr2, int E) {
    int e = blockIdx.x * blockDim.x + threadIdx.x;
    if (e >= E) return;
    size_t st = ei_stride(ei);
    int s = ei[(size_t)e * st];
    int d = ei[((size_t)E + e) * st];
    int2 c;
    c.x = s;
    c.y = __float_as_int(dinv[s] * dinv[d]);
    csr2[rowptr[d] + aux[e]] = c;
}

__global__ __launch_bounds__(256)
void gemm2_kernel(const unsigned short* __restrict__ Xb, const unsigned short* __restrict__ wT_hi,
                  const unsigned short* __restrict__ wT_lo, unsigned short* __restrict__ Yb,
                  int nrows) {
    gemm_core<128, 64, false>(Xb, wT_hi, wT_lo, Yb, nrows, blockIdx.x);
}

// ---------------------------------------------------------------------------
// Gather layer 1 (F=128, bf16 in/out, weighted, relu+dropout fused). 8-deep.
// ---------------------------------------------------------------------------
__global__ __launch_bounds__(256)
void gather_drop(const unsigned* __restrict__ hs /*bf16x2*/, const int2* __restrict__ csr2,
                 const unsigned* __restrict__ rowptr, const float* __restrict__ dinv,
                 const float* __restrict__ bias, unsigned* __restrict__ outb /*bf16x2*/,
                 int N) {
    const int node = blockIdx.x * 4 + (threadIdx.x >> 6);
    if (node >= N) return;
    const int lane = threadIdx.x & 63;
    const unsigned beg = rowptr[node];
    const unsigned end = rowptr[node + 1];   // multiple of 8; pads have w=0
    const float dn = dinv[node];
    const float dn2 = dn * dn;

    unsigned v = hs[(size_t)node * 64 + lane];
    float ax = dn2 * __uint_as_float(v << 16);
    float ay = dn2 * __uint_as_float(v & 0xffff0000u);
    for (unsigned k = beg; k < end; k += 8) {
        int2 c[8];
#pragma unroll
        for (int u = 0; u < 8; ++u) c[u] = csr2[k + u];
        unsigned w8[8];
#pragma unroll
        for (int u = 0; u < 8; ++u) w8[u] = hs[(size_t)c[u].x * 64 + lane];
#pragma unroll
        for (int u = 0; u < 8; ++u) {
            float w = __int_as_float(c[u].y);
            ax = fmaf(w, __uint_as_float(w8[u] << 16), ax);
            ay = fmaf(w, __uint_as_float(w8[u] & 0xffff0000u), ay);
        }
    }
    const int f0 = 2 * lane;
    float o0 = fmaxf(ax + bias[f0], 0.0f);
    float o1 = fmaxf(ay + bias[f0 + 1], 0.0f);
    unsigned base = (unsigned)node * 128u + (unsigned)f0;
    o0 = dropout_keep(base) ? 2.0f * o0 : 0.0f;
    o1 = dropout_keep(base + 1u) ? 2.0f * o1 : 0.0f;
    outb[(size_t)node * 64 + lane] =
        (unsigned)bf16_rn(o0) | ((unsigned)bf16_rn(o1) << 16);
}

// ---------------------------------------------------------------------------
// Gather layer 2 (F=64, bf16 in, f32 out, weighted). 8-deep.
// ---------------------------------------------------------------------------
__global__ __launch_bounds__(256)
void gather_out(const unsigned short* __restrict__ hs /*bf16*/, const int2* __restrict__ csr2,
                const unsigned* __restrict__ rowptr, const float* __restrict__ dinv,
                const float* __restrict__ bias, float* __restrict__ outp, int N) {
    const int node = blockIdx.x * 4 + (threadIdx.x >> 6);
    if (node >= N) return;
    const int lane = threadIdx.x & 63;
    const unsigned beg = rowptr[node];
    const unsigned end = rowptr[node + 1];
    const float dn = dinv[node];

    float acc = dn * dn * __uint_as_float(((unsigned)hs[(size_t)node * 64 + lane]) << 16);
    for (unsigned k = beg; k < end; k += 8) {
        int2 c[8];
#pragma unroll
        for (int u = 0; u < 8; ++u) c[u] = csr2[k + u];
        unsigned short w8[8];
#pragma unroll
        for (int u = 0; u < 8; ++u) w8[u] = hs[(size_t)c[u].x * 64 + lane];
#pragma unroll
        for (int u = 0; u < 8; ++u)
            acc = fmaf(__int_as_float(c[u].y), __uint_as_float(((unsigned)w8[u]) << 16), acc);
    }
    outp[(size_t)node * 64 + lane] = acc + bias[lane];
}

extern "C" void kernel_launch(void* const* d_in, const int* in_sizes, int n_in,
                              void* d_out, int out_size, void* d_ws, size_t ws_size,
                              hipStream_t stream) {
    const float* x  = (const float*)d_in[0];
    const int*   ei = (const int*)d_in[1];
    const float* W1 = (const float*)d_in[2];
    const float* b1 = (const float*)d_in[3];
    const float* W2 = (const float*)d_in[4];
    const float* b2 = (const float*)d_in[5];
    float* out = (float*)d_out;

    const int Fdim = 256, Hdim = 128, Cdim = 64;
    const int N = in_sizes[0] / Fdim;   // 50000
    const int E = in_sizes[1] / 2;      // 800000
    const int CSR_CAP = E + 7 * N;      // padded-slot upper bound
    const int NB = (N + 255) / 256;     // scan blocks (196, <=256 required)

    // workspace: wT1_hi|lo | wT2_hi|lo | buffA[N*128] bf16 | buffB[N*128] bf16 |
    //   deg[N] | dinv[N] | rowptr[N+1] | blockSums[NB] | aux[E] | csr2[CSR_CAP] (int2)
    unsigned short* wT1_hi = (unsigned short*)d_ws;
    unsigned short* wT1_lo = wT1_hi + 256 * 128;
    unsigned short* wT2_hi = wT1_lo + 256 * 128;
    unsigned short* wT2_lo = wT2_hi + 128 * 64;
    unsigned short* buffA  = wT2_lo + 128 * 64;
    unsigned short* buffB  = buffA + (size_t)N * Hdim;
    unsigned* deg    = (unsigned*)(buffB + (size_t)N * Hdim);
    float*    dinv   = (float*)(deg + N);
    unsigned* rowptr = (unsigned*)(dinv + N);
    unsigned* blockSums = rowptr + (N + 1);
    unsigned* aux    = blockSums + NB;
    uintptr_t csr_p  = ((uintptr_t)(aux + E) + 15) & ~(uintptr_t)15;
    int2*     csr2   = (int2*)csr_p;

    const int nGemm1 = (N + 63) / 64;
    const int nCount = (E + 255) / 256;

    // K0: weight split ∥ deg zeroing
    prep<<<160 + (N + 255) / 256, 256, 0, stream>>>(W1, W2, wT1_hi, wT1_lo, wT2_hi, wT2_lo, deg, N);
    // K1: gemm1 (raw bf16 h) ∥ count_slot
    mega1<<<nGemm1 + nCount, 256, 0, stream>>>(x, wT1_hi, wT1_lo, buffA, ei, deg, aux, N, E, nGemm1);
    // CSR finish
    scan_phase1<<<NB, 256, 0, stream>>>(deg, blockSums, dinv, N);
    scan_phase3b<<<NB, 256, 0, stream>>>(deg, blockSums, rowptr, csr2, N, NB);
    place_edges<<<nCount, 256, 0, stream>>>(ei, rowptr, aux, dinv, csr2, E);

    // layer 1 aggregate + relu + dropout
    gather_drop<<<(N + 3) / 4, 256, 0, stream>>>((const unsigned*)buffA, csr2, rowptr, dinv, b1,
                                                 (unsigned*)buffB, N);
    // layer 2
    gemm2_kernel<<<(N + 63) / 64, 256, 0, stream>>>(buffB, wT2_hi, wT2_lo, buffA, N);
    gather_out<<<(N + 3) / 4, 256, 0, stream>>>(buffA, csr2, rowptr, dinv, b2, out, N);
}

// Round 11
// 232.935 us; speedup vs baseline: 1.0621x; 1.0621x over previous
//
#include <hip/hip_runtime.h>

// ---------------------------------------------------------------------------
// GCN 2-layer forward, CSR gather with per-edge dinv lookup:
//   h = X @ W (raw bf16);  out[i] = dn_i*( Σ_j dinv[j]*h_j + dn_i*h_i ) + b
// CSR entries = src only (4B); pads -> node N with dinv[N]=0 (exact zero).
// GEMM: B-fragments loaded direct from global (no W LDS staging) -> 10KB LDS.
// K1 fuses gemm1 ∥ count_slot. GEMM1 split-bf16 (3 MFMA), GEMM2 bf16 A (2).
// Dropout mask = JAX threefry2x32, key(42), partitionable fold (o0^o1), p=0.5.
//   (verified rounds 3-10)
// ---------------------------------------------------------------------------

typedef __attribute__((ext_vector_type(8))) short bf16x8;          // MFMA A/B
typedef __attribute__((ext_vector_type(4))) float f32x4;           // MFMA C/D
typedef __attribute__((ext_vector_type(8))) unsigned short us8;

__device__ __forceinline__ unsigned tf_rotl(unsigned x, int d) {
    return (x << d) | (x >> (32 - d));
}

__device__ __forceinline__ bool dropout_keep(unsigned flat_idx) {
    const unsigned K0 = 0u, K1 = 42u;
    const unsigned K2 = K0 ^ K1 ^ 0x1BD11BDAu;
    unsigned x0 = 0u, x1 = flat_idx;
    x0 += K0; x1 += K1;
#define TF_R(r) { x0 += x1; x1 = tf_rotl(x1, (r)); x1 ^= x0; }
    TF_R(13) TF_R(15) TF_R(26) TF_R(6)
    x0 += K1; x1 += K2 + 1u;
    TF_R(17) TF_R(29) TF_R(16) TF_R(24)
    x0 += K2; x1 += K0 + 2u;
    TF_R(13) TF_R(15) TF_R(26) TF_R(6)
    x0 += K0; x1 += K1 + 3u;
    TF_R(17) TF_R(29) TF_R(16) TF_R(24)
    x0 += K1; x1 += K2 + 4u;
    TF_R(13) TF_R(15) TF_R(26) TF_R(6)
    x0 += K2; x1 += K0 + 5u;
#undef TF_R
    return (((x0 ^ x1) >> 31) & 1u) == 0u;   // fold bits1^bits2, keep if < 2^31
}

// ---- bf16 helpers ----------------------------------------------------------
__device__ __forceinline__ unsigned short bf16_rn(float x) {
    unsigned u = __float_as_uint(x);
    unsigned r = u + 0x7FFFu + ((u >> 16) & 1u);
    return (unsigned short)(r >> 16);
}
__device__ __forceinline__ void split_bf16(float x, unsigned short& h, unsigned short& l) {
    h = bf16_rn(x);
    float fh = __uint_as_float(((unsigned)h) << 16);
    l = bf16_rn(x - fh);
}
__device__ __forceinline__ void split4(float4 v, ushort4& h, ushort4& l) {
    unsigned short h0, h1, h2, h3, l0, l1, l2, l3;
    split_bf16(v.x, h0, l0); split_bf16(v.y, h1, l1);
    split_bf16(v.z, h2, l2); split_bf16(v.w, h3, l3);
    h = make_ushort4(h0, h1, h2, h3);
    l = make_ushort4(l0, l1, l2, l3);
}

// int32 vs int64 edge-index autodetect (values < 50000 -> i64 hi words are 0).
__device__ __forceinline__ int ei_stride(const int* __restrict__ ei) {
    bool i64 = true;
#pragma unroll
    for (int k = 1; k <= 15; k += 2) i64 = i64 && (ei[k] == 0);
    return i64 ? 2 : 1;
}

// ---------------------------------------------------------------------------
// gemm core: Yb[r, NOUT_] = bf16( X[r,:] @ W ), MFMA 16x16x32, BM=64, BK=32.
// B-fragments: direct global loads from wT (L2-resident), reg double-buffered.
// ---------------------------------------------------------------------------
template <int K_, int NOUT_, bool SPLITA>
__device__ __forceinline__ void gemm_core(const void* __restrict__ Xv,
                                          const unsigned short* __restrict__ wT_hi,
                                          const unsigned short* __restrict__ wT_lo,
                                          unsigned short* __restrict__ Yb,
                                          int nrows, int bid) {
    constexpr int BM = 64, BK = 32, NKT = K_ / BK;
    constexpr int CT = NOUT_ / 64;            // col-tiles per wave
    constexpr int LDW = BK + 8;               // 80B row stride (16B multiple)

    __shared__ __attribute__((aligned(16))) unsigned short xs_hi[BM][LDW];
    __shared__ __attribute__((aligned(16))) unsigned short xs_lo[SPLITA ? BM : 1][SPLITA ? LDW : 1];

    const int t = threadIdx.x;
    const int wave = t >> 6, lane = t & 63;
    const int m16 = lane & 15, kg = lane >> 4;
    const int row0 = bid * BM;
    const int n0 = wave * (16 * CT);

    const float* Xf = (const float*)Xv;
    const unsigned short* Xb = (const unsigned short*)Xv;

    f32x4 acc[4][CT];
#pragma unroll
    for (int r = 0; r < 4; ++r)
#pragma unroll
        for (int c = 0; c < CT; ++c) acc[r][c] = {0.f, 0.f, 0.f, 0.f};

    float4 xpre[2];
    us8 xpre_b;
    bf16x8 bh[2][CT], bl[2][CT];

    // prefetch K-step 0: x and B-frags
    if constexpr (SPLITA) {
#pragma unroll
        for (int i = 0; i < 2; ++i) {
            int idx = t + i * 256;
            int r = idx >> 3, c4 = idx & 7;
            int gr = row0 + r;
            xpre[i] = (gr < nrows) ? *(const float4*)&Xf[(size_t)gr * K_ + c4 * 4]
                                   : make_float4(0.f, 0.f, 0.f, 0.f);
        }
    } else {
        int r = t >> 2, c8 = t & 3;
        int gr = row0 + r;
        xpre_b = (gr < nrows) ? *(const us8*)&Xb[(size_t)gr * K_ + c8 * 8] : (us8)0;
    }
#pragma unroll
    for (int c = 0; c < CT; ++c) {
        const size_t wrow = (size_t)(n0 + c * 16 + m16) * K_ + kg * 8;
        bh[0][c] = *(const bf16x8*)&wT_hi[wrow];
        bl[0][c] = *(const bf16x8*)&wT_lo[wrow];
    }

#pragma unroll
    for (int kb = 0; kb < NKT; ++kb) {
        const int cur = kb & 1, nxt = cur ^ 1;
        // stage prefetched x -> LDS
        if constexpr (SPLITA) {
#pragma unroll
            for (int i = 0; i < 2; ++i) {
                int idx = t + i * 256;
                int r = idx >> 3, c4 = idx & 7;
                ushort4 h, l;
                split4(xpre[i], h, l);
                *(ushort4*)&xs_hi[r][c4 * 4] = h;
                *(ushort4*)&xs_lo[r][c4 * 4] = l;
            }
        } else {
            int r = t >> 2, c8 = t & 3;
            *(us8*)&xs_hi[r][c8 * 8] = xpre_b;
        }
        __syncthreads();

        // issue next K-step's loads (x + B-frags) to hide latency under MFMA
        if (kb + 1 < NKT) {
            const int koff = (kb + 1) * BK;
            if constexpr (SPLITA) {
#pragma unroll
                for (int i = 0; i < 2; ++i) {
                    int idx = t + i * 256;
                    int r = idx >> 3, c4 = idx & 7;
                    int gr = row0 + r;
                    xpre[i] = (gr < nrows) ? *(const float4*)&Xf[(size_t)gr * K_ + koff + c4 * 4]
                                           : make_float4(0.f, 0.f, 0.f, 0.f);
                }
            } else {
                int r = t >> 2, c8 = t & 3;
                int gr = row0 + r;
                xpre_b = (gr < nrows) ? *(const us8*)&Xb[(size_t)gr * K_ + koff + c8 * 8] : (us8)0;
            }
#pragma unroll
            for (int c = 0; c < CT; ++c) {
                const size_t wrow = (size_t)(n0 + c * 16 + m16) * K_ + koff + kg * 8;
                bh[nxt][c] = *(const bf16x8*)&wT_hi[wrow];
                bl[nxt][c] = *(const bf16x8*)&wT_lo[wrow];
            }
        }

#pragma unroll
        for (int r = 0; r < 4; ++r) {
            bf16x8 ah = *(const bf16x8*)&xs_hi[r * 16 + m16][kg * 8];
            if constexpr (SPLITA) {
                bf16x8 al = *(const bf16x8*)&xs_lo[r * 16 + m16][kg * 8];
#pragma unroll
                for (int c = 0; c < CT; ++c) {
                    acc[r][c] = __builtin_amdgcn_mfma_f32_16x16x32_bf16(ah, bh[cur][c], acc[r][c], 0, 0, 0);
                    acc[r][c] = __builtin_amdgcn_mfma_f32_16x16x32_bf16(ah, bl[cur][c], acc[r][c], 0, 0, 0);
                    acc[r][c] = __builtin_amdgcn_mfma_f32_16x16x32_bf16(al, bh[cur][c], acc[r][c], 0, 0, 0);
                }
            } else {
#pragma unroll
                for (int c = 0; c < CT; ++c) {
                    acc[r][c] = __builtin_amdgcn_mfma_f32_16x16x32_bf16(ah, bh[cur][c], acc[r][c], 0, 0, 0);
                    acc[r][c] = __builtin_amdgcn_mfma_f32_16x16x32_bf16(ah, bl[cur][c], acc[r][c], 0, 0, 0);
                }
            }
        }
        __syncthreads();
    }

#pragma unroll
    for (int r = 0; r < 4; ++r) {
#pragma unroll
        for (int j = 0; j < 4; ++j) {
            int gr = row0 + r * 16 + kg * 4 + j;
            if (gr < nrows) {
#pragma unroll
                for (int c = 0; c < CT; ++c)
                    Yb[(size_t)gr * NOUT_ + n0 + c * 16 + m16] = bf16_rn(acc[r][c][j]);
            }
        }
    }
}

// ---------------------------------------------------------------------------
// K0: weight split (blocks 0..159) ∥ deg zeroing (rest).
// ---------------------------------------------------------------------------
__global__ __launch_bounds__(256)
void prep(const float* __restrict__ W1, const float* __restrict__ W2,
          unsigned short* __restrict__ wT1_hi, unsigned short* __restrict__ wT1_lo,
          unsigned short* __restrict__ wT2_hi, unsigned short* __restrict__ wT2_lo,
          unsigned* __restrict__ deg, int N) {
    const int b = blockIdx.x, t = threadIdx.x;
    if (b < 160) {
        int idx = b * 256 + t;
        unsigned short h, l;
        if (idx < 256 * 128) {
            int k = idx / 128, n = idx % 128;
            split_bf16(W1[idx], h, l);
            wT1_hi[(size_t)n * 256 + k] = h;
            wT1_lo[(size_t)n * 256 + k] = l;
        } else if (idx < 256 * 128 + 128 * 64) {
            int j = idx - 256 * 128;
            int k = j / 64, n = j % 64;
            split_bf16(W2[j], h, l);
            wT2_hi[(size_t)n * 128 + k] = h;
            wT2_lo[(size_t)n * 128 + k] = l;
        }
    } else {
        int i = (b - 160) * 256 + t;
        if (i < N) deg[i] = 0;
    }
}

// ---------------------------------------------------------------------------
// K1: gemm1 (blocks 0..nGemm-1) ∥ count_slot (rest).
// ---------------------------------------------------------------------------
__global__ __launch_bounds__(256)
void mega1(const float* __restrict__ x, const unsigned short* __restrict__ wT1_hi,
           const unsigned short* __restrict__ wT1_lo, unsigned short* __restrict__ buffA,
           const int* __restrict__ ei, unsigned* __restrict__ deg,
           unsigned* __restrict__ aux, int N, int E, int nGemm) {
    if ((int)blockIdx.x < nGemm) {
        gemm_core<256, 128, true>(x, wT1_hi, wT1_lo, buffA, N, blockIdx.x);
        return;
    }
    int e = (blockIdx.x - nGemm) * 256 + threadIdx.x;
    if (e >= E) return;
    size_t st = ei_stride(ei);
    aux[e] = atomicAdd(&deg[ei[((size_t)E + e) * st]], 1u);
}

// ---------------------------------------------------------------------------
// scan phase1: per-block padded-deg sums + dinv (dinv[N]=0 for pads).
// ---------------------------------------------------------------------------
__global__ __launch_bounds__(256)
void scan_phase1(const unsigned* __restrict__ deg, unsigned* __restrict__ blockSums,
                 float* __restrict__ dinv, int N) {
    const int i = blockIdx.x * 256 + threadIdx.x;
    const int lane = threadIdx.x & 63, wave = threadIdx.x >> 6;
    if (blockIdx.x == 0 && threadIdx.x == 0) dinv[N] = 0.0f;   // zero-node weight
    unsigned v = 0;
    if (i < N) {
        unsigned d = deg[i];
        v = (d + 7u) & ~7u;
        dinv[i] = rsqrtf((float)(d + 1u));   // +1 = self loop
    }
    unsigned s = v;
#pragma unroll
    for (int o = 32; o > 0; o >>= 1) s += __shfl_down(s, o, 64);
    __shared__ unsigned ws[4];
    if (lane == 0) ws[wave] = s;
    __syncthreads();
    if (threadIdx.x == 0)
        blockSums[blockIdx.x] = ws[0] + ws[1] + ws[2] + ws[3];
}

// phase3b: inline scan of block sums + local scan -> rowptr; pads -> node N.
__global__ __launch_bounds__(256)
void scan_phase3b(const unsigned* __restrict__ deg, const unsigned* __restrict__ blockSums,
                  unsigned* __restrict__ rowptr, int* __restrict__ csr, int N, int nb) {
    __shared__ unsigned s[256];
    const int t = threadIdx.x;

    unsigned bsv = (t < nb) ? blockSums[t] : 0u;
    s[t] = bsv;
    __syncthreads();
    for (int off = 1; off < 256; off <<= 1) {
        unsigned u = (t >= off) ? s[t - off] : 0u;
        __syncthreads();
        s[t] += u;
        __syncthreads();
    }
    const unsigned off0 = (blockIdx.x == 0) ? 0u : s[blockIdx.x - 1];
    __syncthreads();

    const int i = blockIdx.x * 256 + t;
    unsigned d = 0, v = 0;
    if (i < N) { d = deg[i]; v = (d + 7u) & ~7u; }
    s[t] = v;
    __syncthreads();
    for (int off = 1; off < 256; off <<= 1) {
        unsigned u = (t >= off) ? s[t - off] : 0u;
        __syncthreads();
        s[t] += u;
        __syncthreads();
    }
    const unsigned incl = s[t];
    if (i < N) {
        const unsigned rp = off0 + incl - v;
        rowptr[i] = rp;
        if (i == N - 1) rowptr[N] = off0 + incl;
        for (unsigned u = d; u < v; ++u) csr[rp + u] = N;   // pad -> zero-weight node
    }
}

// atomic-free placement: csr[slot] = src (4B)
__global__ void place_edges(const int* __restrict__ ei, const unsigned* __restrict__ rowptr,
                            const unsigned* __restrict__ aux, int* __restrict__ csr, int E) {
    int e = blockIdx.x * blockDim.x + threadIdx.x;
    if (e >= E) return;
    size_t st = ei_stride(ei);
    int s = ei[(size_t)e * st];
    int d = ei[((size_t)E + e) * st];
    csr[rowptr[d] + aux[e]] = s;
}

__global__ __launch_bounds__(256)
void gemm2_kernel(const unsigned short* __restrict__ Xb, const unsigned short* __restrict__ wT_hi,
                  const unsigned short* __restrict__ wT_lo, unsigned short* __restrict__ Yb,
                  int nrows) {
    gemm_core<128, 64, false>(Xb, wT_hi, wT_lo, Yb, nrows, blockIdx.x);
}

// ---------------------------------------------------------------------------
// Gather layer 1 (F=128, bf16 in/out, relu+dropout fused). 8-deep batches.
// out = dn*( Σ dinv[j]*h_j + dn*h_i ) + b
// ---------------------------------------------------------------------------
__global__ __launch_bounds__(256)
void gather_drop(const unsigned* __restrict__ hs /*bf16x2*/, const int* __restrict__ csr,
                 const unsigned* __restrict__ rowptr, const float* __restrict__ dinv,
                 const float* __restrict__ bias, unsigned* __restrict__ outb /*bf16x2*/,
                 int N) {
    const int node = blockIdx.x * 4 + (threadIdx.x >> 6);
    if (node >= N) return;
    const int lane = threadIdx.x & 63;
    const unsigned beg = rowptr[node];
    const unsigned end = rowptr[node + 1];   // multiple of 8; pads -> node N (dinv 0)
    const float dn = dinv[node];

    unsigned v = hs[(size_t)node * 64 + lane];
    float ax = dn * __uint_as_float(v << 16);
    float ay = dn * __uint_as_float(v & 0xffff0000u);
    for (unsigned k = beg; k < end; k += 8) {
        int j[8];
#pragma unroll
        for (int u = 0; u < 8; ++u) j[u] = csr[k + u];
        unsigned w8[8];
        float dv[8];
#pragma unroll
        for (int u = 0; u < 8; ++u) { w8[u] = hs[(size_t)j[u] * 64 + lane]; dv[u] = dinv[j[u]]; }
#pragma unroll
        for (int u = 0; u < 8; ++u) {
            ax = fmaf(dv[u], __uint_as_float(w8[u] << 16), ax);
            ay = fmaf(dv[u], __uint_as_float(w8[u] & 0xffff0000u), ay);
        }
    }
    const int f0 = 2 * lane;
    float o0 = fmaxf(fmaf(dn, ax, bias[f0]), 0.0f);
    float o1 = fmaxf(fmaf(dn, ay, bias[f0 + 1]), 0.0f);
    unsigned base = (unsigned)node * 128u + (unsigned)f0;
    o0 = dropout_keep(base) ? 2.0f * o0 : 0.0f;
    o1 = dropout_keep(base + 1u) ? 2.0f * o1 : 0.0f;
    outb[(size_t)node * 64 + lane] =
        (unsigned)bf16_rn(o0) | ((unsigned)bf16_rn(o1) << 16);
}

// ---------------------------------------------------------------------------
// Gather layer 2 (F=64, bf16 in, f32 out). 8-deep batches.
// ---------------------------------------------------------------------------
__global__ __launch_bounds__(256)
void gather_out(const unsigned short* __restrict__ hs /*bf16*/, const int* __restrict__ csr,
                const unsigned* __restrict__ rowptr, const float* __restrict__ dinv,
                const float* __restrict__ bias, float* __restrict__ outp, int N) {
    const int node = blockIdx.x * 4 + (threadIdx.x >> 6);
    if (node >= N) return;
    const int lane = threadIdx.x & 63;
    const unsigned beg = rowptr[node];
    const unsigned end = rowptr[node + 1];
    const float dn = dinv[node];

    float acc = dn * __uint_as_float(((unsigned)hs[(size_t)node * 64 + lane]) << 16);
    for (unsigned k = beg; k < end; k += 8) {
        int j[8];
#pragma unroll
        for (int u = 0; u < 8; ++u) j[u] = csr[k + u];
        unsigned short w8[8];
        float dv[8];
#pragma unroll
        for (int u = 0; u < 8; ++u) { w8[u] = hs[(size_t)j[u] * 64 + lane]; dv[u] = dinv[j[u]]; }
#pragma unroll
        for (int u = 0; u < 8; ++u)
            acc = fmaf(dv[u], __uint_as_float(((unsigned)w8[u]) << 16), acc);
    }
    outp[(size_t)node * 64 + lane] = fmaf(dn, acc, bias[lane]);
}

extern "C" void kernel_launch(void* const* d_in, const int* in_sizes, int n_in,
                              void* d_out, int out_size, void* d_ws, size_t ws_size,
                              hipStream_t stream) {
    const float* x  = (const float*)d_in[0];
    const int*   ei = (const int*)d_in[1];
    const float* W1 = (const float*)d_in[2];
    const float* b1 = (const float*)d_in[3];
    const float* W2 = (const float*)d_in[4];
    const float* b2 = (const float*)d_in[5];
    float* out = (float*)d_out;

    const int Fdim = 256, Hdim = 128, Cdim = 64;
    const int N = in_sizes[0] / Fdim;   // 50000
    const int E = in_sizes[1] / 2;      // 800000
    const int CSR_CAP = E + 7 * N;      // padded-slot upper bound
    const int NB = (N + 255) / 256;     // scan blocks (196, <=256 required)

    // workspace: wT1_hi|lo | wT2_hi|lo | buffA[(N+1)*128] bf16 | buffB[N*128] bf16 |
    //   deg[N] | dinv[N+1] | rowptr[N+1] | blockSums[NB] | aux[E] | csr[CSR_CAP]
    unsigned short* wT1_hi = (unsigned short*)d_ws;
    unsigned short* wT1_lo = wT1_hi + 256 * 128;
    unsigned short* wT2_hi = wT1_lo + 256 * 128;
    unsigned short* wT2_lo = wT2_hi + 128 * 64;
    unsigned short* buffA  = wT2_lo + 128 * 64;
    unsigned short* buffB  = buffA + (size_t)(N + 1) * Hdim;
    unsigned* deg    = (unsigned*)(buffB + (size_t)N * Hdim);
    float*    dinv   = (float*)(deg + N);
    unsigned* rowptr = (unsigned*)(dinv + (N + 1));
    unsigned* blockSums = rowptr + (N + 1);
    unsigned* aux    = blockSums + NB;
    int*      csr    = (int*)(aux + E);

    const int nGemm1 = (N + 63) / 64;
    const int nCount = (E + 255) / 256;

    // K0: weight split ∥ deg zeroing
    prep<<<160 + NB, 256, 0, stream>>>(W1, W2, wT1_hi, wT1_lo, wT2_hi, wT2_lo, deg, N);
    // K1: gemm1 (raw bf16 h) ∥ count_slot
    mega1<<<nGemm1 + nCount, 256, 0, stream>>>(x, wT1_hi, wT1_lo, buffA, ei, deg, aux, N, E, nGemm1);
    // CSR finish
    scan_phase1<<<NB, 256, 0, stream>>>(deg, blockSums, dinv, N);
    scan_phase3b<<<NB, 256, 0, stream>>>(deg, blockSums, rowptr, csr, N, NB);
    place_edges<<<nCount, 256, 0, stream>>>(ei, rowptr, aux, csr, E);

    // layer 1 aggregate + relu + dropout
    gather_drop<<<(N + 3) / 4, 256, 0, stream>>>((const unsigned*)buffA, csr, rowptr, dinv, b1,
                                                 (unsigned*)buffB, N);
    // layer 2
    gemm2_kernel<<<(N + 63) / 64, 256, 0, stream>>>(buffB, wT2_hi, wT2_lo, buffA, N);
    gather_out<<<(N + 3) / 4, 256, 0, stream>>>(buffA, csr, rowptr, dinv, b2, out, N);
}